// Round 2
// baseline (788.906 us; speedup 1.0000x reference)
//
#include <hip/hip_runtime.h>
#include <math.h>

#define B_ 16
#define P_ 25
#define S_ 1024
#define D_ 128
#define H_ 8
#define DH_ 16
#define DFF_ 512
#define SIGMA_ 0.1f

// out layout (floats):
// r_:0  z:51200  pred:102400  w:102800  K_res:103200  V_res:52532000  I_new:104960800

// ---------------- K1: q,k,v projections ----------------
__global__ __launch_bounds__(128) void qkv_kernel(
    const float* __restrict__ x, const float* __restrict__ Wq,
    const float* __restrict__ Wk, const float* __restrict__ Wv,
    const float* __restrict__ eps_k, const float* __restrict__ eps_v,
    float* __restrict__ q, float* __restrict__ k, float* __restrict__ v) {
  int bp = blockIdx.x;  // 0..399
  int d = threadIdx.x;  // 0..127
  __shared__ float xs[D_];
  xs[d] = x[bp * D_ + d];
  __syncthreads();
  float accq = 0.f, acck = 0.f, accv = 0.f;
  for (int i = 0; i < D_; ++i) {
    float xv = xs[i];
    accq += xv * Wq[i * D_ + d];
    acck += xv * Wk[i * D_ + d];
    accv += xv * Wv[i * D_ + d];
  }
  q[bp * D_ + d] = accq;
  k[bp * D_ + d] = acck + SIGMA_ * eps_k[bp * D_ + d];
  v[bp * D_ + d] = accv + SIGMA_ * eps_v[bp * D_ + d];
}

// ---------------- K2: attention (flash-decode, 8 waves split s) ----------------
__global__ __launch_bounds__(512) void attn_kernel(
    const float* __restrict__ q, const float* __restrict__ kn,
    const float* __restrict__ vn, const float* __restrict__ K,
    const float* __restrict__ V, const int* __restrict__ tptr,
    float* __restrict__ ctx) {
  int bp = blockIdx.x;  // 0..399
  int t = tptr[0];
  int tid = threadIdx.x;
  int wave = tid >> 6;  // 0..7
  int lane = tid & 63;
  __shared__ float qs[D_];
  __shared__ float accs[8][D_];
  __shared__ float ms[8][H_];
  __shared__ float ls[8][H_];
  if (tid < D_) qs[tid] = q[bp * D_ + tid] * 0.25f;  // 1/sqrt(DH)
  __syncthreads();
  const float* Kb = K + (size_t)bp * S_ * D_;
  const float* Vb = V + (size_t)bp * S_ * D_;
  float m = -1e30f, l = 0.f, a0 = 0.f, a1 = 0.f;
  float q0 = qs[2 * lane], q1 = qs[2 * lane + 1];
  for (int s = wave; s <= t; s += 8) {
    const float* Kr, *Vr;
    if (s == t) { Kr = kn + bp * D_; Vr = vn + bp * D_; }
    else        { Kr = Kb + (size_t)s * D_; Vr = Vb + (size_t)s * D_; }
    float2 kk = *(const float2*)(Kr + 2 * lane);
    float2 vv = *(const float2*)(Vr + 2 * lane);
    float p = q0 * kk.x + q1 * kk.y;
    p += __shfl_xor(p, 1);
    p += __shfl_xor(p, 2);
    p += __shfl_xor(p, 4);  // score for head lane>>3, in all 8 lanes of group
    float mnew = fmaxf(m, p);
    float scale = expf(m - mnew);
    float e = expf(p - mnew);
    l = l * scale + e;
    a0 = a0 * scale + e * vv.x;
    a1 = a1 * scale + e * vv.y;
    m = mnew;
  }
  accs[wave][2 * lane] = a0;
  accs[wave][2 * lane + 1] = a1;
  if ((lane & 7) == 0) { ms[wave][lane >> 3] = m; ls[wave][lane >> 3] = l; }
  __syncthreads();
  if (tid < D_) {
    int h = tid >> 4;
    float mg = -1e30f;
    for (int w2 = 0; w2 < 8; ++w2) mg = fmaxf(mg, ms[w2][h]);
    float L = 0.f, C = 0.f;
    for (int w2 = 0; w2 < 8; ++w2) {
      float sc = expf(ms[w2][h] - mg);
      L += ls[w2][h] * sc;
      C += accs[w2][tid] * sc;
    }
    ctx[bp * D_ + tid] = C / L;
  }
}

// ---------------- K3: Wo + eps_z, FFN, pred ----------------
__global__ __launch_bounds__(512) void head_kernel(
    const float* __restrict__ ctx, const float* __restrict__ Wo,
    const float* __restrict__ eps_z, const float* __restrict__ W1,
    const float* __restrict__ b1, const float* __restrict__ W2,
    const float* __restrict__ b2, const float* __restrict__ Wout,
    const float* __restrict__ bout, float* __restrict__ out_r,
    float* __restrict__ out_z, float* __restrict__ out_pred) {
  int bp = blockIdx.x;
  int tid = threadIdx.x;
  __shared__ float cs[D_];
  __shared__ float zs[D_];
  __shared__ float as[DFF_];
  __shared__ float rs[D_];
  if (tid < D_) cs[tid] = ctx[bp * D_ + tid];
  __syncthreads();
  if (tid < D_) {
    float acc = 0.f;
    for (int i = 0; i < D_; ++i) acc += cs[i] * Wo[i * D_ + tid];
    acc += SIGMA_ * eps_z[bp * D_ + tid];
    zs[tid] = acc;
    out_z[bp * D_ + tid] = acc;
  }
  __syncthreads();
  {
    float acc = b1[tid];
    for (int i = 0; i < D_; ++i) acc += zs[i] * W1[i * DFF_ + tid];
    as[tid] = fmaxf(acc, 0.f);
  }
  __syncthreads();
  if (tid < D_) {
    float acc = b2[tid];
    for (int j = 0; j < DFF_; ++j) acc += as[j] * W2[j * D_ + tid];
    rs[tid] = acc;
    out_r[bp * D_ + tid] = acc;
  }
  __syncthreads();
  if (tid < 64) {
    float acc = rs[tid] * Wout[tid] + rs[tid + 64] * Wout[tid + 64];
    acc += __shfl_xor(acc, 1);
    acc += __shfl_xor(acc, 2);
    acc += __shfl_xor(acc, 4);
    acc += __shfl_xor(acc, 8);
    acc += __shfl_xor(acc, 16);
    acc += __shfl_xor(acc, 32);
    if (tid == 0) out_pred[bp] = acc + bout[0];
  }
}

// ---------------- K4: weights + threefry categorical sampling ----------------
__device__ inline unsigned rotl_(unsigned x, int r) {
  return (x << r) | (x >> (32 - r));
}

__device__ inline void threefry2x32_(unsigned x0, unsigned x1, unsigned& o0,
                                     unsigned& o1) {
  const unsigned k0 = 0u, k1 = 42u;
  const unsigned k2 = k0 ^ k1 ^ 0x1BD11BDAu;
  x0 += k0; x1 += k1;
#define RND_(r) { x0 += x1; x1 = rotl_(x1, r); x1 ^= x0; }
  RND_(13) RND_(15) RND_(26) RND_(6)   x0 += k1; x1 += k2 + 1u;
  RND_(17) RND_(29) RND_(16) RND_(24)  x0 += k2; x1 += k0 + 2u;
  RND_(13) RND_(15) RND_(26) RND_(6)   x0 += k0; x1 += k1 + 3u;
  RND_(17) RND_(29) RND_(16) RND_(24)  x0 += k1; x1 += k2 + 4u;
  RND_(13) RND_(15) RND_(26) RND_(6)   x0 += k2; x1 += k0 + 5u;
#undef RND_
  o0 = x0; o1 = x1;
}

__device__ inline float gumbel_at_(int n) {
  // JAX partitionable threefry (default since 0.4.36):
  // counts = iota_2x32_shape -> (hi, lo) = (0, n) for n < 2^32
  // bits = o0 ^ o1 for bit_width 32
  unsigned o0, o1;
  threefry2x32_(0u, (unsigned)n, o0, o1);
  unsigned bits = o0 ^ o1;
  unsigned fb = (bits >> 9) | 0x3f800000u;
  float f = __uint_as_float(fb) - 1.0f;
  const float tiny = 1.1754944e-38f;
  float u = fmaxf(tiny, f * (1.0f - tiny) + tiny);
  return -logf(-logf(u));
}

__global__ __launch_bounds__(64) void sample_kernel(
    const float* __restrict__ pred, const float* __restrict__ y,
    float* __restrict__ out_w, int* __restrict__ idx) {
  int b = blockIdx.x;  // 0..15
  int tid = threadIdx.x;
  __shared__ float lw[P_];
  __shared__ float logits[P_];
  __shared__ float red[2];
  if (tid < P_) {
    float mu = y[b * 4] - pred[b * P_ + tid];
    lw[tid] = -0.25f * (mu * mu);  // -0.5*OMEGA
  }
  __syncthreads();
  if (tid == 0) {
    float mn = lw[0];
    for (int p = 1; p < P_; ++p) mn = fminf(mn, lw[p]);
    red[0] = mn;
  }
  __syncthreads();
  if (tid < P_) lw[tid] = expf(lw[tid] - red[0]);
  __syncthreads();
  if (tid == 0) {
    float s = 0.f;
    for (int p = 0; p < P_; ++p) s += lw[p];
    red[1] = s;
  }
  __syncthreads();
  if (tid < P_) {
    float wn = lw[tid] / red[1];
    out_w[b * P_ + tid] = wn;
    logits[tid] = logf(wn + 1e-10f);
  }
  __syncthreads();
  if (tid < P_) {
    float best = -1e30f;
    int bestj = 0;
    for (int j = 0; j < P_; ++j) {
      int n = (b * P_ + tid) * P_ + j;
      float val = gumbel_at_(n) + logits[j];
      if (val > best) { best = val; bestj = j; }  // first-index tie-break
    }
    idx[b * P_ + tid] = bestj;
  }
}

// ---------------- K5: gather K_res / V_res ----------------
__global__ __launch_bounds__(256) void gather_kernel(
    const float* __restrict__ K, const float* __restrict__ V,
    const float* __restrict__ kn, const float* __restrict__ vn,
    const int* __restrict__ idx, const int* __restrict__ tptr,
    float* __restrict__ outK, float* __restrict__ outV) {
  const int CH = 4;                       // chunks per row
  const int F4 = (S_ * D_ / 4) / CH;      // 8192 float4 per chunk
  int bid = blockIdx.x;                   // 0..3199
  int tv = bid / (B_ * P_ * CH);
  int rem = bid - tv * (B_ * P_ * CH);
  int bp = rem / CH;
  int chunk = rem - bp * CH;
  int b = bp / P_;
  int j = idx[bp];
  int t = tptr[0];
  const float* src = (tv == 0 ? K : V) + (size_t)(b * P_ + j) * (S_ * D_);
  const float4* sub = (const float4*)((tv == 0 ? kn : vn) + (b * P_ + j) * D_);
  float* dst = (tv == 0 ? outK : outV) + (size_t)bp * (S_ * D_);
  const float4* src4 = (const float4*)src;
  float4* dst4 = (float4*)dst;
  int base = chunk * F4;
  int tlo = t * (D_ / 4);
  for (int i = base + threadIdx.x; i < base + F4; i += 256) {
    float4 val;
    if (i >= tlo && i < tlo + D_ / 4) val = sub[i - tlo];
    else                              val = src4[i];
    dst4[i] = val;
  }
}

// ---------------- K6: I_new (ints written as float values) ----------------
__global__ __launch_bounds__(256) void inew_kernel(
    const int* __restrict__ I, const int* __restrict__ idx,
    const int* __restrict__ tptr, float* __restrict__ outI) {
  int bp = blockIdx.x;
  int b = bp / P_;
  int j = idx[bp];
  int t = tptr[0];
  const int* src = I + (b * P_ + j) * S_;
  float* dst = outI + bp * S_;
  for (int s = threadIdx.x; s < S_; s += 256) {
    int val = (s == t) ? j : src[s];
    dst[s] = (float)val;
  }
}

extern "C" void kernel_launch(void* const* d_in, const int* in_sizes, int n_in,
                              void* d_out, int out_size, void* d_ws,
                              size_t ws_size, hipStream_t stream) {
  const float* x     = (const float*)d_in[0];
  const float* y     = (const float*)d_in[1];
  const float* K     = (const float*)d_in[2];
  const float* V     = (const float*)d_in[3];
  const int*   I     = (const int*)d_in[5];
  const float* Wq    = (const float*)d_in[6];
  const float* Wk    = (const float*)d_in[7];
  const float* Wv    = (const float*)d_in[8];
  const float* Wo    = (const float*)d_in[9];
  const float* W1    = (const float*)d_in[10];
  const float* b1    = (const float*)d_in[11];
  const float* W2    = (const float*)d_in[12];
  const float* b2    = (const float*)d_in[13];
  const float* Wout  = (const float*)d_in[14];
  const float* bout  = (const float*)d_in[15];
  const float* eps_k = (const float*)d_in[16];
  const float* eps_v = (const float*)d_in[17];
  const float* eps_z = (const float*)d_in[18];
  const int*   tptr  = (const int*)d_in[19];

  float* out      = (float*)d_out;
  float* out_r    = out;
  float* out_z    = out + 51200;
  float* out_pred = out + 102400;
  float* out_w    = out + 102800;
  float* outK     = out + 103200;
  float* outV     = outK + (size_t)52428800;
  float* outI     = outV + (size_t)52428800;

  float* ws  = (float*)d_ws;
  float* q   = ws;
  float* k   = ws + 51200;
  float* v   = ws + 102400;
  float* ctx = ws + 153600;
  int*   idx = (int*)(ws + 204800);

  qkv_kernel<<<B_ * P_, 128, 0, stream>>>(x, Wq, Wk, Wv, eps_k, eps_v, q, k, v);
  attn_kernel<<<B_ * P_, 512, 0, stream>>>(q, k, v, K, V, tptr, ctx);
  head_kernel<<<B_ * P_, 512, 0, stream>>>(ctx, Wo, eps_z, W1, b1, W2, b2, Wout,
                                           bout, out_r, out_z, out_pred);
  sample_kernel<<<B_, 64, 0, stream>>>(out_pred, y, out_w, idx);
  gather_kernel<<<B_ * P_ * 4 * 2, 256, 0, stream>>>(K, V, k, v, idx, tptr,
                                                     outK, outV);
  inew_kernel<<<B_ * P_, 256, 0, stream>>>(I, idx, tptr, outI);
}